// Round 7
// baseline (728.292 us; speedup 1.0000x reference)
//
#include <hip/hip_runtime.h>
#include <math.h>

#define NN 100000
#define NE 1600000
#define D 64
#define DE 32
#define NB_SCAN ((NN + 255) / 256)   // 391

typedef __attribute__((ext_vector_type(8))) short short8;
typedef __attribute__((ext_vector_type(4))) float f32x4;

__device__ __forceinline__ int rfl(int v){ return __builtin_amdgcn_readfirstlane(v); }

#define LEAKY(v) ((v) > 0.f ? (v) : 0.2f*(v))

__device__ __forceinline__ unsigned short f2bf(float x){
  unsigned u = __float_as_uint(x);
  unsigned r = (u + 0x7fffu + ((u >> 16) & 1u)) >> 16;
  return (unsigned short)r;
}
__device__ __forceinline__ float bf2f(unsigned short b){
  return __uint_as_float(((unsigned)b) << 16);
}

// cursor doubles as deg accumulator
__global__ __launch_bounds__(256) void k_deg(const int* __restrict__ dst, int* __restrict__ cursor){
  int i = blockIdx.x*256 + threadIdx.x;
  if (i < NE) atomicAdd(&cursor[dst[i]], 1);
}

__global__ __launch_bounds__(256) void k_scan_a(const int* __restrict__ deg, int* __restrict__ bsum){
  __shared__ int sh[256];
  int tid = threadIdx.x;
  int i = blockIdx.x*256 + tid;
  sh[tid] = (i < NN) ? deg[i] : 0;
  __syncthreads();
  for (int s = 128; s > 0; s >>= 1){
    if (tid < s) sh[tid] += sh[tid+s];
    __syncthreads();
  }
  if (tid == 0) bsum[blockIdx.x] = sh[0];
}

__global__ __launch_bounds__(512) void k_scan_b(int* __restrict__ bsum, int* __restrict__ rowptr){
  __shared__ int tmp[512];
  int tid = threadIdx.x;
  int v = (tid < NB_SCAN) ? bsum[tid] : 0;
  tmp[tid] = v;
  __syncthreads();
  for (int off = 1; off < 512; off <<= 1){
    int t = (tid >= off) ? tmp[tid-off] : 0;
    __syncthreads();
    tmp[tid] += t;
    __syncthreads();
  }
  if (tid < NB_SCAN) bsum[tid] = tmp[tid] - v;
  if (tid == 511) rowptr[NN] = tmp[511];
}

// reads cursor (=deg), writes rowptr and resets cursor to the exclusive offset
__global__ __launch_bounds__(256) void k_scan_c(const int* bsum, int* rowptr, int* cursor){
  __shared__ int tmp[256];
  int tid = threadIdx.x;
  int i = blockIdx.x*256 + tid;
  int v = (i < NN) ? cursor[i] : 0;
  tmp[tid] = v;
  __syncthreads();
  for (int off = 1; off < 256; off <<= 1){
    int t = (tid >= off) ? tmp[tid-off] : 0;
    __syncthreads();
    tmp[tid] += t;
    __syncthreads();
  }
  if (i < NN){
    int excl = tmp[tid] - v + bsum[blockIdx.x];
    rowptr[i] = excl;
    cursor[i] = excl;
  }
}

// slot[pos]=edge id of CSR slot, ssrc[pos]=src node of CSR slot
__global__ __launch_bounds__(256) void k_scatter(const int* __restrict__ srcp, const int* __restrict__ dstp,
                                                 int* __restrict__ cursor,
                                                 int* __restrict__ slot, int* __restrict__ ssrc){
  int i = blockIdx.x*256 + threadIdx.x;
  if (i < NE){
    int d = dstp[i];
    int pos = atomicAdd(&cursor[d], 1);
    slot[pos] = i;
    ssrc[pos] = srcp[i];
  }
}

// t_csr[i][j] = bf16( (eattr[slot[i]] @ We)[j] ) via mfma, SWAPPED operands:
// A = We-slice (dims x K), B = 16 gathered eattr rows (K x edges).
// D: lane(r,g) -> edge i0+r, dims 16m+4g+0..3  => one ushort4 store per MFMA.
// Two tiles unrolled; both layers' We in one pass over eattr.
__global__ __launch_bounds__(256) void k_t(const float* __restrict__ eattr,
                                           const int* __restrict__ slot,
                                           const float* __restrict__ We1,
                                           const float* __restrict__ We2,
                                           unsigned short* __restrict__ t1,
                                           unsigned short* __restrict__ t2){
  int lane = threadIdx.x & 63;
  int wid = blockIdx.x*(blockDim.x>>6) + (threadIdx.x>>6);
  int nw = gridDim.x*(blockDim.x>>6);
  int r = lane & 15;
  int g = lane >> 4;
  // A fragments: wa[m][j] = We[(8g+j)][16m + r]
  short8 wa1[4], wa2[4];
  #pragma unroll
  for (int m = 0; m < 4; ++m){
    #pragma unroll
    for (int j = 0; j < 8; ++j){
      wa1[m][j] = (short)f2bf(We1[(8*g + j)*D + 16*m + r]);
      wa2[m][j] = (short)f2bf(We2[(8*g + j)*D + 16*m + r]);
    }
  }
  for (int i0 = wid*32; i0 < NE; i0 += nw*32){   // NE % 32 == 0, no tail
    int slA = slot[i0 + r];
    int slB = slot[i0 + 16 + r];
    const float* eaA = eattr + (size_t)slA*DE + 8*g;
    const float* eaB = eattr + (size_t)slB*DE + 8*g;
    float4 a0 = *(const float4*)(eaA);
    float4 a1 = *(const float4*)(eaA + 4);
    float4 b0 = *(const float4*)(eaB);
    float4 b1 = *(const float4*)(eaB + 4);
    short8 ba, bb;
    ba[0]=(short)f2bf(a0.x); ba[1]=(short)f2bf(a0.y); ba[2]=(short)f2bf(a0.z); ba[3]=(short)f2bf(a0.w);
    ba[4]=(short)f2bf(a1.x); ba[5]=(short)f2bf(a1.y); ba[6]=(short)f2bf(a1.z); ba[7]=(short)f2bf(a1.w);
    bb[0]=(short)f2bf(b0.x); bb[1]=(short)f2bf(b0.y); bb[2]=(short)f2bf(b0.z); bb[3]=(short)f2bf(b0.w);
    bb[4]=(short)f2bf(b1.x); bb[5]=(short)f2bf(b1.y); bb[6]=(short)f2bf(b1.z); bb[7]=(short)f2bf(b1.w);
    #pragma unroll
    for (int half = 0; half < 2; ++half){
      short8 bf_ = half ? bb : ba;
      int base = i0 + 16*half;
      size_t rowb = (size_t)(base + r)*D + 4*g;
      #pragma unroll
      for (int m = 0; m < 4; ++m){
        f32x4 d1 = {0.f,0.f,0.f,0.f};
        d1 = __builtin_amdgcn_mfma_f32_16x16x32_bf16(wa1[m], bf_, d1, 0, 0, 0);
        ushort4 pk1;
        pk1.x = f2bf(d1[0]); pk1.y = f2bf(d1[1]); pk1.z = f2bf(d1[2]); pk1.w = f2bf(d1[3]);
        *(ushort4*)(t1 + rowb + 16*m) = pk1;
      }
      #pragma unroll
      for (int m = 0; m < 4; ++m){
        f32x4 d2 = {0.f,0.f,0.f,0.f};
        d2 = __builtin_amdgcn_mfma_f32_16x16x32_bf16(wa2[m], bf_, d2, 0, 0, 0);
        ushort4 pk2;
        pk2.x = f2bf(d2[0]); pk2.y = f2bf(d2[1]); pk2.z = f2bf(d2[2]); pk2.w = f2bf(d2[3]);
        *(ushort4*)(t2 + rowb + 16*m) = pk2;
      }
    }
  }
}

// xl[n][j] = b[j] + sum_k x[n][k]*W[k][j]
__global__ __launch_bounds__(256) void k_lin(const float* __restrict__ xin, const float* __restrict__ W,
                                             const float* __restrict__ b, float* __restrict__ xl){
  int lane = threadIdx.x & 63;
  int wid = blockIdx.x*(blockDim.x>>6) + (threadIdx.x>>6);
  int nw = gridDim.x*(blockDim.x>>6);
  float wcol[D];
  #pragma unroll
  for (int kk = 0; kk < D; ++kk) wcol[kk] = W[kk*D + lane];
  float bj = b[lane];
  for (int n0 = wid; n0 < NN; n0 += nw){
    int n = rfl(n0);
    const float* xr = xin + (size_t)n*D;
    float acc = bj;
    #pragma unroll
    for (int kk = 0; kk < D; ++kk) acc = fmaf(xr[kk], wcol[kk], acc);
    xl[(size_t)n*D + lane] = acc;
  }
}

#define RED64(c) { _Pragma("unroll") for (int off = 32; off > 0; off >>= 1) c += __shfl_xor(c, off, 64); }

// Fused per-destination: logit + softmax + aggregate. Unroll-8 with hoisted loads.
__global__ __launch_bounds__(256) void k_node(const int* __restrict__ rowptr,
                                              const int* __restrict__ ssrc,
                                              const unsigned short* __restrict__ t_csr,
                                              const float* __restrict__ att,
                                              const float* __restrict__ xl,
                                              const float* __restrict__ bias,
                                              float* __restrict__ outp){
  int lane = threadIdx.x & 63;
  int wid = blockIdx.x*(blockDim.x>>6) + (threadIdx.x>>6);
  int nw = gridDim.x*(blockDim.x>>6);
  float attj = att[lane];
  float bj = bias[lane];
  for (int n0 = wid; n0 < NN; n0 += nw){
    int n = rfl(n0);
    int st = rowptr[n], en = rowptr[n+1];
    float xd = xl[(size_t)n*D + lane];
    float tsum = 0.f;
    float den0 = 0.f, den1 = 0.f, acc0 = 0.f, acc1 = 0.f;
    int i = st;
    for (; i + 8 <= en; i += 8){
      int ss[8]; float tt[8], xs[8], cc[8];
      #pragma unroll
      for (int k = 0; k < 8; ++k) ss[k] = ssrc[i+k];
      #pragma unroll
      for (int k = 0; k < 8; ++k) tt[k] = bf2f(t_csr[(size_t)(i+k)*D + lane]);
      #pragma unroll
      for (int k = 0; k < 8; ++k) xs[k] = xl[(size_t)ss[k]*D + lane];
      #pragma unroll
      for (int k = 0; k < 8; ++k){
        tsum += tt[k];
        float m = LEAKY(xs[k] + xd + tt[k]);
        cc[k] = m * attj;
      }
      #pragma unroll
      for (int off = 32; off > 0; off >>= 1){
        #pragma unroll
        for (int k = 0; k < 8; ++k) cc[k] += __shfl_xor(cc[k], off, 64);
      }
      #pragma unroll
      for (int k = 0; k < 8; ++k){
        float p = __expf(cc[k]);
        if (k & 1){ den1 += p; acc1 = fmaf(p, xs[k], acc1); }
        else      { den0 += p; acc0 = fmaf(p, xs[k], acc0); }
      }
    }
    for (; i + 4 <= en; i += 4){
      int ss[4]; float tt[4], xs[4], cc[4];
      #pragma unroll
      for (int k = 0; k < 4; ++k) ss[k] = ssrc[i+k];
      #pragma unroll
      for (int k = 0; k < 4; ++k) tt[k] = bf2f(t_csr[(size_t)(i+k)*D + lane]);
      #pragma unroll
      for (int k = 0; k < 4; ++k) xs[k] = xl[(size_t)ss[k]*D + lane];
      #pragma unroll
      for (int k = 0; k < 4; ++k){
        tsum += tt[k];
        float m = LEAKY(xs[k] + xd + tt[k]);
        cc[k] = m * attj;
      }
      #pragma unroll
      for (int off = 32; off > 0; off >>= 1){
        #pragma unroll
        for (int k = 0; k < 4; ++k) cc[k] += __shfl_xor(cc[k], off, 64);
      }
      #pragma unroll
      for (int k = 0; k < 4; ++k){
        float p = __expf(cc[k]);
        if (k & 1){ den1 += p; acc1 = fmaf(p, xs[k], acc1); }
        else      { den0 += p; acc0 = fmaf(p, xs[k], acc0); }
      }
    }
    for (; i < en; ++i){
      int s = ssrc[i];
      float t = bf2f(t_csr[(size_t)i*D + lane]);
      float xs = xl[(size_t)s*D + lane];
      tsum += t;
      float c = LEAKY(xs + xd + t) * attj;
      RED64(c)
      float p = __expf(c);
      den0 += p;
      acc0 = fmaf(p, xs, acc0);
    }
    // self loop: t_self = mean(t_e) by linearity; 0 for isolated nodes
    float degf = (float)(en - st);
    float ts = tsum / fmaxf(degf, 1.f);
    float cs = LEAKY(xd + xd + ts) * attj;
    RED64(cs)
    float ps = __expf(cs);
    float den = den0 + den1 + ps;
    float acc = fmaf(ps, xd, acc0 + acc1);
    outp[(size_t)n*D + lane] = acc/den + bj;
  }
}

extern "C" void kernel_launch(void* const* d_in, const int* in_sizes, int n_in,
                              void* d_out, int out_size, void* d_ws, size_t ws_size,
                              hipStream_t stream){
  const float* x     = (const float*)d_in[0];
  const int*   ei    = (const int*)d_in[1];
  const float* eattr = (const float*)d_in[2];
  const float* W1    = (const float*)d_in[3];
  const float* b1    = (const float*)d_in[4];
  const float* We1   = (const float*)d_in[5];
  const float* att1  = (const float*)d_in[6];
  const float* bias1 = (const float*)d_in[7];
  const float* W2    = (const float*)d_in[8];
  const float* b2    = (const float*)d_in[9];
  const float* We2   = (const float*)d_in[10];
  const float* att2  = (const float*)d_in[11];
  const float* bias2 = (const float*)d_in[12];
  const int* srcp = ei;
  const int* dstp = ei + NE;
  float* out = (float*)d_out;

  char* p = (char*)d_ws;
  size_t off = 0;
  auto alloc = [&](size_t bytes)->char*{
    char* r = p + off; off = (off + bytes + 255) & ~(size_t)255; return r;
  };
  int* rowptr   = (int*)alloc((size_t)(NN+1)*4);
  int* cursor   = (int*)alloc((size_t)NN*4);       // also deg accumulator
  int* bsum     = (int*)alloc(512*4);
  int* slot     = (int*)alloc((size_t)NE*4);
  int* ssrc     = (int*)alloc((size_t)NE*4);
  float* xl     = (float*)alloc((size_t)NN*D*4);
  float* h      = (float*)alloc((size_t)NN*D*4);
  unsigned short* t1 = (unsigned short*)alloc((size_t)NE*D*2);  // 204.8 MB
  unsigned short* t2 = (unsigned short*)alloc((size_t)NE*D*2);  // 204.8 MB

  hipMemsetAsync(cursor, 0, (size_t)NN*4, stream);
  k_deg     <<<(NE+255)/256, 256, 0, stream>>>(dstp, cursor);
  k_scan_a  <<<NB_SCAN, 256, 0, stream>>>(cursor, bsum);
  k_scan_b  <<<1, 512, 0, stream>>>(bsum, rowptr);
  k_scan_c  <<<NB_SCAN, 256, 0, stream>>>(bsum, rowptr, cursor);
  k_scatter <<<(NE+255)/256, 256, 0, stream>>>(srcp, dstp, cursor, slot, ssrc);

  // one eattr pass computes both layers' edge transforms
  k_t   <<<2048, 256, 0, stream>>>(eattr, slot, We1, We2, t1, t2);
  k_lin <<<2048, 256, 0, stream>>>(x, W1, b1, xl);
  k_node<<<4096, 256, 0, stream>>>(rowptr, ssrc, t1, att1, xl, bias1, h);
  k_lin <<<2048, 256, 0, stream>>>(h, W2, b2, xl);
  k_node<<<4096, 256, 0, stream>>>(rowptr, ssrc, t2, att2, xl, bias2, out);
}

// Round 8
// 697.851 us; speedup vs baseline: 1.0436x; 1.0436x over previous
//
#include <hip/hip_runtime.h>
#include <math.h>

#define NN 100000
#define NE 1600000
#define D 64
#define DE 32
#define NB_SCAN ((NN + 255) / 256)   // 391

typedef __attribute__((ext_vector_type(8))) short short8;
typedef __attribute__((ext_vector_type(4))) float f32x4;

__device__ __forceinline__ int rfl(int v){ return __builtin_amdgcn_readfirstlane(v); }

#define LEAKY(v) ((v) > 0.f ? (v) : 0.2f*(v))

__device__ __forceinline__ unsigned short f2bf(float x){
  unsigned u = __float_as_uint(x);
  unsigned r = (u + 0x7fffu + ((u >> 16) & 1u)) >> 16;
  return (unsigned short)r;
}
__device__ __forceinline__ float bf2f(unsigned short b){
  return __uint_as_float(((unsigned)b) << 16);
}

// cursor doubles as deg accumulator
__global__ __launch_bounds__(256) void k_deg(const int* __restrict__ dst, int* __restrict__ cursor){
  int i = blockIdx.x*256 + threadIdx.x;
  if (i < NE) atomicAdd(&cursor[dst[i]], 1);
}

__global__ __launch_bounds__(256) void k_scan_a(const int* __restrict__ deg, int* __restrict__ bsum){
  __shared__ int sh[256];
  int tid = threadIdx.x;
  int i = blockIdx.x*256 + tid;
  sh[tid] = (i < NN) ? deg[i] : 0;
  __syncthreads();
  for (int s = 128; s > 0; s >>= 1){
    if (tid < s) sh[tid] += sh[tid+s];
    __syncthreads();
  }
  if (tid == 0) bsum[blockIdx.x] = sh[0];
}

__global__ __launch_bounds__(512) void k_scan_b(int* __restrict__ bsum, int* __restrict__ rowptr){
  __shared__ int tmp[512];
  int tid = threadIdx.x;
  int v = (tid < NB_SCAN) ? bsum[tid] : 0;
  tmp[tid] = v;
  __syncthreads();
  for (int off = 1; off < 512; off <<= 1){
    int t = (tid >= off) ? tmp[tid-off] : 0;
    __syncthreads();
    tmp[tid] += t;
    __syncthreads();
  }
  if (tid < NB_SCAN) bsum[tid] = tmp[tid] - v;
  if (tid == 511) rowptr[NN] = tmp[511];
}

// reads cursor (=deg), writes rowptr and resets cursor to the exclusive offset
__global__ __launch_bounds__(256) void k_scan_c(const int* bsum, int* rowptr, int* cursor){
  __shared__ int tmp[256];
  int tid = threadIdx.x;
  int i = blockIdx.x*256 + tid;
  int v = (i < NN) ? cursor[i] : 0;
  tmp[tid] = v;
  __syncthreads();
  for (int off = 1; off < 256; off <<= 1){
    int t = (tid >= off) ? tmp[tid-off] : 0;
    __syncthreads();
    tmp[tid] += t;
    __syncthreads();
  }
  if (i < NN){
    int excl = tmp[tid] - v + bsum[blockIdx.x];
    rowptr[i] = excl;
    cursor[i] = excl;
  }
}

// slot[pos]=edge id of CSR slot, ssrc[pos]=src node of CSR slot
__global__ __launch_bounds__(256) void k_scatter(const int* __restrict__ srcp, const int* __restrict__ dstp,
                                                 int* __restrict__ cursor,
                                                 int* __restrict__ slot, int* __restrict__ ssrc){
  int i = blockIdx.x*256 + threadIdx.x;
  if (i < NE){
    int d = dstp[i];
    int pos = atomicAdd(&cursor[d], 1);
    slot[pos] = i;
    ssrc[pos] = srcp[i];
  }
}

// t_csr[i][j] = bf16( (eattr[slot[i]] @ We)[j] )  via mfma_f32_16x16x32_bf16.
// One wave per 16 CSR slots (R6-proven body, 48 VGPR). Random 128B-aligned row
// reads (vector loads), sequential writes. Both layers in one eattr pass.
__global__ __launch_bounds__(256) void k_t(const float* __restrict__ eattr,
                                           const int* __restrict__ slot,
                                           const float* __restrict__ We1,
                                           const float* __restrict__ We2,
                                           unsigned short* __restrict__ t1,
                                           unsigned short* __restrict__ t2){
  int lane = threadIdx.x & 63;
  int wid = blockIdx.x*(blockDim.x>>6) + (threadIdx.x>>6);
  int nw = gridDim.x*(blockDim.x>>6);
  int r = lane & 15;    // A: edge row within tile; B/D: output col within 16-tile
  int g = lane >> 4;    // k-group (A/B), row-group (D)
  // B fragments: wb[t][i] = We[(8g+i)][16t + r]
  short8 wb1[4], wb2[4];
  #pragma unroll
  for (int t = 0; t < 4; ++t){
    #pragma unroll
    for (int i = 0; i < 8; ++i){
      wb1[t][i] = (short)f2bf(We1[(8*g + i)*D + 16*t + r]);
      wb2[t][i] = (short)f2bf(We2[(8*g + i)*D + 16*t + r]);
    }
  }
  for (int i0 = wid*16; i0 < NE; i0 += nw*16){
    int sl = slot[i0 + r];
    const float* ea = eattr + (size_t)sl*DE + 8*g;
    float4 q0 = *(const float4*)(ea);
    float4 q1 = *(const float4*)(ea + 4);
    short8 a;
    a[0]=(short)f2bf(q0.x); a[1]=(short)f2bf(q0.y); a[2]=(short)f2bf(q0.z); a[3]=(short)f2bf(q0.w);
    a[4]=(short)f2bf(q1.x); a[5]=(short)f2bf(q1.y); a[6]=(short)f2bf(q1.z); a[7]=(short)f2bf(q1.w);
    f32x4 d0={0.f,0.f,0.f,0.f}, d1={0.f,0.f,0.f,0.f}, d2={0.f,0.f,0.f,0.f}, d3={0.f,0.f,0.f,0.f};
    d0 = __builtin_amdgcn_mfma_f32_16x16x32_bf16(a, wb1[0], d0, 0, 0, 0);
    d1 = __builtin_amdgcn_mfma_f32_16x16x32_bf16(a, wb1[1], d1, 0, 0, 0);
    d2 = __builtin_amdgcn_mfma_f32_16x16x32_bf16(a, wb1[2], d2, 0, 0, 0);
    d3 = __builtin_amdgcn_mfma_f32_16x16x32_bf16(a, wb1[3], d3, 0, 0, 0);
    size_t rb = (size_t)(i0 + 4*g)*D + r;   // row 4g+i, col 16t+r
    #pragma unroll
    for (int i = 0; i < 4; ++i){
      t1[rb + (size_t)i*D +  0] = f2bf(d0[i]);
      t1[rb + (size_t)i*D + 16] = f2bf(d1[i]);
      t1[rb + (size_t)i*D + 32] = f2bf(d2[i]);
      t1[rb + (size_t)i*D + 48] = f2bf(d3[i]);
    }
    f32x4 e0={0.f,0.f,0.f,0.f}, e1={0.f,0.f,0.f,0.f}, e2={0.f,0.f,0.f,0.f}, e3={0.f,0.f,0.f,0.f};
    e0 = __builtin_amdgcn_mfma_f32_16x16x32_bf16(a, wb2[0], e0, 0, 0, 0);
    e1 = __builtin_amdgcn_mfma_f32_16x16x32_bf16(a, wb2[1], e1, 0, 0, 0);
    e2 = __builtin_amdgcn_mfma_f32_16x16x32_bf16(a, wb2[2], e2, 0, 0, 0);
    e3 = __builtin_amdgcn_mfma_f32_16x16x32_bf16(a, wb2[3], e3, 0, 0, 0);
    #pragma unroll
    for (int i = 0; i < 4; ++i){
      t2[rb + (size_t)i*D +  0] = f2bf(e0[i]);
      t2[rb + (size_t)i*D + 16] = f2bf(e1[i]);
      t2[rb + (size_t)i*D + 32] = f2bf(e2[i]);
      t2[rb + (size_t)i*D + 48] = f2bf(e3[i]);
    }
  }
}

// xl[n][j] = b[j] + sum_k x[n][k]*W[k][j]
__global__ __launch_bounds__(256) void k_lin(const float* __restrict__ xin, const float* __restrict__ W,
                                             const float* __restrict__ b, float* __restrict__ xl){
  int lane = threadIdx.x & 63;
  int wid = blockIdx.x*(blockDim.x>>6) + (threadIdx.x>>6);
  int nw = gridDim.x*(blockDim.x>>6);
  float wcol[D];
  #pragma unroll
  for (int kk = 0; kk < D; ++kk) wcol[kk] = W[kk*D + lane];
  float bj = b[lane];
  for (int n0 = wid; n0 < NN; n0 += nw){
    int n = rfl(n0);
    const float* xr = xin + (size_t)n*D;
    float acc = bj;
    #pragma unroll
    for (int kk = 0; kk < D; ++kk) acc = fmaf(xr[kk], wcol[kk], acc);
    xl[(size_t)n*D + lane] = acc;
  }
}

#define RED64(c) { _Pragma("unroll") for (int off = 32; off > 0; off >>= 1) c += __shfl_xor(c, off, 64); }

// Fused per-destination: logit + softmax + aggregate. Software-pipelined:
// batch i+1's ssrc/t/xs loads issue before batch i's compute.
__global__ __launch_bounds__(256) void k_node(const int* __restrict__ rowptr,
                                              const int* __restrict__ ssrc,
                                              const unsigned short* __restrict__ t_csr,
                                              const float* __restrict__ att,
                                              const float* __restrict__ xl,
                                              const float* __restrict__ bias,
                                              float* __restrict__ outp){
  int lane = threadIdx.x & 63;
  int wid = blockIdx.x*(blockDim.x>>6) + (threadIdx.x>>6);
  int nw = gridDim.x*(blockDim.x>>6);
  float attj = att[lane];
  float bj = bias[lane];
  for (int n0 = wid; n0 < NN; n0 += nw){
    int n = rfl(n0);
    int st = rowptr[n], en = rowptr[n+1];
    float xd = xl[(size_t)n*D + lane];
    float tsum = 0.f;
    float den0 = 0.f, den1 = 0.f, acc0 = 0.f, acc1 = 0.f;
    int i = st;
    // ---- pipelined batches of 4 ----
    int ssA0=0, ssA1=0, ssA2=0, ssA3=0;
    float ttA0=0, ttA1=0, ttA2=0, ttA3=0;
    float xsA0=0, xsA1=0, xsA2=0, xsA3=0;
    bool haveA = (i + 4 <= en);
    if (haveA){
      ssA0 = ssrc[i]; ssA1 = ssrc[i+1]; ssA2 = ssrc[i+2]; ssA3 = ssrc[i+3];
      ttA0 = bf2f(t_csr[(size_t)(i  )*D + lane]);
      ttA1 = bf2f(t_csr[(size_t)(i+1)*D + lane]);
      ttA2 = bf2f(t_csr[(size_t)(i+2)*D + lane]);
      ttA3 = bf2f(t_csr[(size_t)(i+3)*D + lane]);
      xsA0 = xl[(size_t)ssA0*D + lane];
      xsA1 = xl[(size_t)ssA1*D + lane];
      xsA2 = xl[(size_t)ssA2*D + lane];
      xsA3 = xl[(size_t)ssA3*D + lane];
    }
    while (haveA){
      int ni = i + 4;
      bool haveB = (ni + 4 <= en);
      int ssB0=0, ssB1=0, ssB2=0, ssB3=0;
      float ttB0=0, ttB1=0, ttB2=0, ttB3=0;
      float xsB0=0, xsB1=0, xsB2=0, xsB3=0;
      if (haveB){
        ssB0 = ssrc[ni]; ssB1 = ssrc[ni+1]; ssB2 = ssrc[ni+2]; ssB3 = ssrc[ni+3];
        ttB0 = bf2f(t_csr[(size_t)(ni  )*D + lane]);
        ttB1 = bf2f(t_csr[(size_t)(ni+1)*D + lane]);
        ttB2 = bf2f(t_csr[(size_t)(ni+2)*D + lane]);
        ttB3 = bf2f(t_csr[(size_t)(ni+3)*D + lane]);
        xsB0 = xl[(size_t)ssB0*D + lane];
        xsB1 = xl[(size_t)ssB1*D + lane];
        xsB2 = xl[(size_t)ssB2*D + lane];
        xsB3 = xl[(size_t)ssB3*D + lane];
      }
      // compute current batch A (loads for B are in flight)
      tsum += (ttA0 + ttA1) + (ttA2 + ttA3);
      float c0 = LEAKY(xsA0 + xd + ttA0) * attj;
      float c1 = LEAKY(xsA1 + xd + ttA1) * attj;
      float c2 = LEAKY(xsA2 + xd + ttA2) * attj;
      float c3 = LEAKY(xsA3 + xd + ttA3) * attj;
      #pragma unroll
      for (int off = 32; off > 0; off >>= 1){
        c0 += __shfl_xor(c0, off, 64);
        c1 += __shfl_xor(c1, off, 64);
        c2 += __shfl_xor(c2, off, 64);
        c3 += __shfl_xor(c3, off, 64);
      }
      float p0 = __expf(c0), p1 = __expf(c1), p2 = __expf(c2), p3 = __expf(c3);
      den0 += p0 + p1;
      den1 += p2 + p3;
      acc0 = fmaf(p0, xsA0, acc0);
      acc0 = fmaf(p1, xsA1, acc0);
      acc1 = fmaf(p2, xsA2, acc1);
      acc1 = fmaf(p3, xsA3, acc1);
      ssA0=ssB0; ssA1=ssB1; ssA2=ssB2; ssA3=ssB3;
      ttA0=ttB0; ttA1=ttB1; ttA2=ttB2; ttA3=ttB3;
      xsA0=xsB0; xsA1=xsB1; xsA2=xsB2; xsA3=xsB3;
      i = ni;
      haveA = haveB;
    }
    // ---- tail ----
    for (; i < en; ++i){
      int s = ssrc[i];
      float t = bf2f(t_csr[(size_t)i*D + lane]);
      float xs = xl[(size_t)s*D + lane];
      tsum += t;
      float c = LEAKY(xs + xd + t) * attj;
      RED64(c)
      float p = __expf(c);
      den0 += p;
      acc0 = fmaf(p, xs, acc0);
    }
    // self loop: t_self = mean(t_e) by linearity; 0 for isolated nodes
    float degf = (float)(en - st);
    float ts = tsum / fmaxf(degf, 1.f);
    float cs = LEAKY(xd + xd + ts) * attj;
    RED64(cs)
    float ps = __expf(cs);
    float den = den0 + den1 + ps;
    float acc = fmaf(ps, xd, acc0 + acc1);
    outp[(size_t)n*D + lane] = acc/den + bj;
  }
}

extern "C" void kernel_launch(void* const* d_in, const int* in_sizes, int n_in,
                              void* d_out, int out_size, void* d_ws, size_t ws_size,
                              hipStream_t stream){
  const float* x     = (const float*)d_in[0];
  const int*   ei    = (const int*)d_in[1];
  const float* eattr = (const float*)d_in[2];
  const float* W1    = (const float*)d_in[3];
  const float* b1    = (const float*)d_in[4];
  const float* We1   = (const float*)d_in[5];
  const float* att1  = (const float*)d_in[6];
  const float* bias1 = (const float*)d_in[7];
  const float* W2    = (const float*)d_in[8];
  const float* b2    = (const float*)d_in[9];
  const float* We2   = (const float*)d_in[10];
  const float* att2  = (const float*)d_in[11];
  const float* bias2 = (const float*)d_in[12];
  const int* srcp = ei;
  const int* dstp = ei + NE;
  float* out = (float*)d_out;

  char* p = (char*)d_ws;
  size_t off = 0;
  auto alloc = [&](size_t bytes)->char*{
    char* r = p + off; off = (off + bytes + 255) & ~(size_t)255; return r;
  };
  int* rowptr   = (int*)alloc((size_t)(NN+1)*4);
  int* cursor   = (int*)alloc((size_t)NN*4);       // also deg accumulator
  int* bsum     = (int*)alloc(512*4);
  int* slot     = (int*)alloc((size_t)NE*4);
  int* ssrc     = (int*)alloc((size_t)NE*4);
  float* xl     = (float*)alloc((size_t)NN*D*4);
  float* h      = (float*)alloc((size_t)NN*D*4);
  unsigned short* t1 = (unsigned short*)alloc((size_t)NE*D*2);  // 204.8 MB
  unsigned short* t2 = (unsigned short*)alloc((size_t)NE*D*2);  // 204.8 MB

  hipMemsetAsync(cursor, 0, (size_t)NN*4, stream);
  k_deg     <<<(NE+255)/256, 256, 0, stream>>>(dstp, cursor);
  k_scan_a  <<<NB_SCAN, 256, 0, stream>>>(cursor, bsum);
  k_scan_b  <<<1, 512, 0, stream>>>(bsum, rowptr);
  k_scan_c  <<<NB_SCAN, 256, 0, stream>>>(bsum, rowptr, cursor);
  k_scatter <<<(NE+255)/256, 256, 0, stream>>>(srcp, dstp, cursor, slot, ssrc);

  // one eattr pass computes both layers' edge transforms
  k_t   <<<4096, 256, 0, stream>>>(eattr, slot, We1, We2, t1, t2);
  k_lin <<<2048, 256, 0, stream>>>(x, W1, b1, xl);
  k_node<<<8192, 256, 0, stream>>>(rowptr, ssrc, t1, att1, xl, bias1, h);
  k_lin <<<2048, 256, 0, stream>>>(h, W2, b2, xl);
  k_node<<<8192, 256, 0, stream>>>(rowptr, ssrc, t2, att2, xl, bias2, out);
}